// Round 5
// baseline (107.162 us; speedup 1.0000x reference)
//
#include <hip/hip_runtime.h>
#include <hip/hip_fp16.h>

// SSIM loss via two banded GEMMs on MFMA (gfx950).
// h-pass: H(48x16) = Data(48x32) x W(32x16), W[k][j]=g[k-j]  (per 16-col tile)
// v-pass: Out(32x16) = Gv(32x48) x H(48x16), Gv[r][k]=g[k-r]
// Product maps (xx,yy,xy) formed elementwise on A-fragments in registers.
// One barrier per block; per-wave private H buffers (no cross-wave sync).

typedef _Float16 f16x8 __attribute__((ext_vector_type(8)));
typedef _Float16 f16x4 __attribute__((ext_vector_type(4)));
typedef float    f32x4 __attribute__((ext_vector_type(4)));

#define BR 32      // out rows per block
#define BC 128     // out cols per block
#define SR 48      // staged rows (42 used, pad to 48 = 3 MFMA row-tiles)
#define SC 152     // staged cols (138 data + pad; 304B row = 19*16B, balanced b128)
#define HR 56      // H row slots per col (48 used; 112B = 7*16B, balanced b128)
#define NBLK (48 * 16 * 4)    // 3072 blocks
#define NPIX 12582912.0

__global__ __launch_bounds__(256) void ssim_mfma_kernel(
    const float* __restrict__ X, const float* __restrict__ Y,
    float* __restrict__ partial)
{
    __shared__ __align__(16) _Float16 sbX[SR][SC];
    __shared__ __align__(16) _Float16 sbY[SR][SC];
    __shared__ __align__(16) _Float16 Hb[4][5][16][HR];  // [wave][map][col][row]

    const int tid = threadIdx.x;
    const int bid = blockIdx.x;
    const int img = bid >> 6;           // 16 row-bands * 4 col-bands = 64
    const int rb  = (bid >> 2) & 15;
    const int cb  = bid & 3;
    const int r0  = rb * BR;
    const int c0  = cb * BC;

    const float* __restrict__ Xi = X + (size_t)img * (512 * 512);
    const float* __restrict__ Yi = Y + (size_t)img * (512 * 512);

    // Gaussian weights (matches jnp construction)
    float g[11];
    {
        float s = 0.f;
        #pragma unroll
        for (int i = 0; i < 11; ++i) {
            float d = (float)(i - 5);
            float e = expf(-d * d * (1.0f / 4.5f));
            g[i] = e; s += e;
        }
        float inv = 1.0f / s;
        #pragma unroll
        for (int i = 0; i < 11; ++i) g[i] *= inv;
    }

    const int lane = tid & 63;
    const int jj   = lane & 15;   // MFMA N-col / M-row within fragment
    const int gq   = lane >> 4;   // 4-lane group -> k-block

    // W fragment (B-operand of h-GEMM): W[k][jj] = g[k-jj], k = 8*gq + v
    f16x8 wfrag;
    #pragma unroll
    for (int v = 0; v < 8; ++v) {
        int k = 8 * gq + v, d = k - jj;
        wfrag[v] = (_Float16)((d >= 0 && d <= 10) ? g[d] : 0.f);
    }
    // Gv fragments (A-operand of v-GEMM): Gv[r][k] = g[k-r], r = 16*rt + jj
    f16x8 gv32[2];
    f16x4 gv16[2];
    #pragma unroll
    for (int rt = 0; rt < 2; ++rt) {
        int r = 16 * rt + jj;
        #pragma unroll
        for (int v = 0; v < 8; ++v) {
            int k = 8 * gq + v, d = k - r;
            gv32[rt][v] = (_Float16)((d >= 0 && d <= 10) ? g[d] : 0.f);
        }
        #pragma unroll
        for (int v = 0; v < 4; ++v) {
            int k = 32 + 4 * gq + v, d = k - r;
            gv16[rt][v] = (_Float16)((d >= 0 && d <= 10) ? g[d] : 0.f);
        }
    }

    // ---- stage X,Y as f16 (zero outside image); coalesced scalar loads ----
    for (int idx = tid; idx < SR * SC; idx += 256) {
        int row = idx / SC;
        int q   = idx - row * SC;
        int gr = r0 - 5 + row, gc = c0 - 5 + q;
        float xv = 0.f, yv = 0.f;
        if ((unsigned)gr < 512u && (unsigned)gc < 512u) {
            size_t o = (size_t)gr * 512 + (size_t)gc;
            xv = Xi[o]; yv = Yi[o];
        }
        sbX[row][q] = (_Float16)xv;
        sbY[row][q] = (_Float16)yv;
    }
    __syncthreads();

    // ---- per-wave: 2 col-tiles, fully independent ----
    const int w = tid >> 6;
    float acc = 0.f;

    #pragma unroll 1
    for (int t = 0; t < 2; ++t) {
        const int jt = 2 * w + t;          // col-tile index 0..7

        // h-GEMM: 3 row-tiles x 5 maps
        f32x4 hacc[3][5];
        #pragma unroll
        for (int rt = 0; rt < 3; ++rt)
            #pragma unroll
            for (int m = 0; m < 5; ++m) hacc[rt][m] = (f32x4)0.f;

        #pragma unroll
        for (int rt = 0; rt < 3; ++rt) {
            const f16x8 ax = *(const f16x8*)&sbX[16 * rt + jj][16 * jt + 8 * gq];
            const f16x8 ay = *(const f16x8*)&sbY[16 * rt + jj][16 * jt + 8 * gq];
            const f16x8 axx = ax * ax;
            const f16x8 ayy = ay * ay;
            const f16x8 axy = ax * ay;
            hacc[rt][0] = __builtin_amdgcn_mfma_f32_16x16x32_f16(ax,  wfrag, hacc[rt][0], 0, 0, 0);
            hacc[rt][1] = __builtin_amdgcn_mfma_f32_16x16x32_f16(ay,  wfrag, hacc[rt][1], 0, 0, 0);
            hacc[rt][2] = __builtin_amdgcn_mfma_f32_16x16x32_f16(axx, wfrag, hacc[rt][2], 0, 0, 0);
            hacc[rt][3] = __builtin_amdgcn_mfma_f32_16x16x32_f16(ayy, wfrag, hacc[rt][3], 0, 0, 0);
            hacc[rt][4] = __builtin_amdgcn_mfma_f32_16x16x32_f16(axy, wfrag, hacc[rt][4], 0, 0, 0);
        }

        // write H (col-major per map): C/D lane holds col jj, rows 16rt+4gq+e
        #pragma unroll
        for (int rt = 0; rt < 3; ++rt)
            #pragma unroll
            for (int m = 0; m < 5; ++m) {
                const int rbase = 16 * rt + 4 * gq;
                f32x4 c = hacc[rt][m];
                _Float16* p = &Hb[w][m][jj][rbase];
                p[0] = (_Float16)c[0];
                p[1] = (_Float16)c[1];
                p[2] = (_Float16)c[2];
                p[3] = (_Float16)c[3];
            }
        asm volatile("s_waitcnt lgkmcnt(0)" ::: "memory");

        // v-GEMM: Out(32x16) = Gv x H, K = 48 (32 + 16)
        f32x4 vacc[2][5];
        #pragma unroll
        for (int rt = 0; rt < 2; ++rt)
            #pragma unroll
            for (int m = 0; m < 5; ++m) vacc[rt][m] = (f32x4)0.f;

        #pragma unroll
        for (int m = 0; m < 5; ++m) {
            const f16x8 b0 = *(const f16x8*)&Hb[w][m][jj][8 * gq];       // k 0..31
            const f16x4 b1 = *(const f16x4*)&Hb[w][m][jj][32 + 4 * gq];  // k 32..47
            vacc[0][m] = __builtin_amdgcn_mfma_f32_16x16x32_f16(gv32[0], b0, vacc[0][m], 0, 0, 0);
            vacc[1][m] = __builtin_amdgcn_mfma_f32_16x16x32_f16(gv32[1], b0, vacc[1][m], 0, 0, 0);
            vacc[0][m] = __builtin_amdgcn_mfma_f32_16x16x16f16(gv16[0], b1, vacc[0][m], 0, 0, 0);
            vacc[1][m] = __builtin_amdgcn_mfma_f32_16x16x16f16(gv16[1], b1, vacc[1][m], 0, 0, 0);
        }

        // SSIM formula on the 8 output px this lane owns
        const float C1 = 1e-4f, C2 = 9e-4f;
        #pragma unroll
        for (int rt = 0; rt < 2; ++rt)
            #pragma unroll
            for (int e = 0; e < 4; ++e) {
                float mu1 = vacc[rt][0][e], mu2 = vacc[rt][1][e];
                float exx = vacc[rt][2][e], eyy = vacc[rt][3][e], exy = vacc[rt][4][e];
                float m11 = mu1 * mu1, m22 = mu2 * mu2, m12 = mu1 * mu2;
                float s1 = exx - m11, s2 = eyy - m22, s12 = exy - m12;
                float num = (2.f * m12 + C1) * (2.f * s12 + C2);
                float den = (m11 + m22 + C1) * (s1 + s2 + C2);
                acc = fmaf(num, __builtin_amdgcn_rcpf(den), acc);
            }
    }

    // ---- block reduction ----
    #pragma unroll
    for (int off = 32; off > 0; off >>= 1)
        acc += __shfl_down(acc, off, 64);

    __shared__ float wsum[4];
    if (lane == 0) wsum[w] = acc;
    __syncthreads();
    if (tid == 0)
        partial[bid] = wsum[0] + wsum[1] + wsum[2] + wsum[3];
}

__global__ __launch_bounds__(256) void ssim_reduce_kernel(
    const float* __restrict__ partial, float* __restrict__ out)
{
    const int tid = threadIdx.x;
    double s = 0.0;
    for (int i = tid; i < NBLK; i += 256) s += (double)partial[i];
    __shared__ double sd[256];
    sd[tid] = s;
    __syncthreads();
    for (int off = 128; off > 0; off >>= 1) {
        if (tid < off) sd[tid] += sd[tid + off];
        __syncthreads();
    }
    if (tid == 0) out[0] = (float)(1.0 - sd[0] / NPIX);
}

extern "C" void kernel_launch(void* const* d_in, const int* in_sizes, int n_in,
                              void* d_out, int out_size, void* d_ws, size_t ws_size,
                              hipStream_t stream) {
    const float* X = (const float*)d_in[0];
    const float* Y = (const float*)d_in[1];
    float* partial = (float*)d_ws;   // NBLK floats = 12 KiB
    float* out = (float*)d_out;

    ssim_mfma_kernel<<<NBLK, 256, 0, stream>>>(X, Y, partial);
    ssim_reduce_kernel<<<1, 256, 0, stream>>>(partial, out);
}

// Round 6
// 61.191 us; speedup vs baseline: 1.7513x; 1.7513x over previous
//
#include <hip/hip_runtime.h>
#include <hip/hip_fp16.h>

// SSIM loss, packed-f16 row-sweep with fully independent waves.
// Each wave owns a 32-row x 128-col output strip; stages its own rows
// (+6-half halo each side) into wave-private LDS double buffers; h-pass
// reads 7 consecutive dwords per map (stride-1, conflict-free) and builds
// odd-offset tap views via funnel shift; 5x11 __half2 register ring;
// v-pass from registers; SSIM formula in f32. ZERO block barriers.

#define ROWS 32
#define NI   (ROWS + 10)         // 42 staged rows per strip
#define NSTRIP 3072              // 48 img * 16 row-bands * 4 col-strips
#define NBLK  (NSTRIP / 4)       // 768 blocks, 4 waves each
#define NPIX  12582912.0

static __device__ __forceinline__ unsigned fun16(unsigned hi, unsigned lo) {
    return (unsigned)((((unsigned long long)hi << 32) | lo) >> 16);  // v_alignbit
}
static __device__ __forceinline__ unsigned h2u(__half2 v) {
    unsigned u; __builtin_memcpy(&u, &v, 4); return u;
}
static __device__ __forceinline__ __half2 u2h(unsigned u) {
    __half2 v; __builtin_memcpy(&v, &u, 4); return v;
}

__global__ __launch_bounds__(256, 3) void ssim_sweep_kernel(
    const float* __restrict__ X, const float* __restrict__ Y,
    float* __restrict__ partial)
{
    // [wave][map][dbuf][word]; word i = half2 (x[cs-6+2i], x[cs-5+2i]); 9216 B
    __shared__ unsigned sbw[4][2][2][72];

    const int tid  = threadIdx.x;
    const int lane = tid & 63;
    const int w    = tid >> 6;
    const int sid  = blockIdx.x * 4 + w;
    const int img  = sid >> 6;
    const int rb   = (sid >> 2) & 15;
    const int cs   = (sid & 3) << 7;    // strip col start
    const int r0   = rb * ROWS;

    const float* __restrict__ Xi = X + (size_t)img * (512 * 512);
    const float* __restrict__ Yi = Y + (size_t)img * (512 * 512);

    // Gaussian weights (matches jnp construction)
    float g[11];
    {
        float s = 0.f;
        #pragma unroll
        for (int i = 0; i < 11; ++i) {
            float d = (float)(i - 5);
            float e = expf(-d * d * (1.0f / 4.5f));
            g[i] = e; s += e;
        }
        float inv = 1.0f / s;
        #pragma unroll
        for (int i = 0; i < 11; ++i) g[i] *= inv;
    }
    __half2 w2[11];
    #pragma unroll
    for (int i = 0; i < 11; ++i) w2[i] = __float2half2_rn(g[i]);

    const int c2 = cs + 2 * lane;       // own 2 cols (always in-image)

    // halo duty: lanes 48-53 -> map0 words {0,1,2,67,68,69}; 56-61 -> map1
    int hq = -1, hm = 0;
    if (lane >= 48 && lane < 54)      { hq = lane - 48; hm = 0; }
    else if (lane >= 56 && lane < 62) { hq = lane - 56; hm = 1; }
    const int  hwd = (hq < 0) ? 0 : (hq < 3 ? hq : 64 + hq);
    const int  hc  = cs - 6 + 2 * hwd;
    const bool hok = (hq >= 0) && ((unsigned)hc < 512u);
    const float* hbase = hm ? Yi : Xi;

    float2 nvx, nvy, nvh;
    #define STAGE_LOAD(J)                                                    \
        {                                                                    \
            int gr = r0 - 5 + (J);                                           \
            nvx = make_float2(0.f, 0.f); nvy = nvx; nvh = nvx;               \
            if ((unsigned)gr < 512u) {                                       \
                const float* xr = Xi + (size_t)gr * 512;                     \
                const float* yr = Yi + (size_t)gr * 512;                     \
                nvx = *(const float2*)(xr + c2);                             \
                nvy = *(const float2*)(yr + c2);                             \
                if (hok) nvh = *(const float2*)(hbase + (size_t)gr * 512 + hc); \
            }                                                                \
        }
    #define STAGE_WRITE(BUF)                                                 \
        {                                                                    \
            sbw[w][0][BUF][3 + lane] = h2u(__floats2half2_rn(nvx.x, nvx.y)); \
            sbw[w][1][BUF][3 + lane] = h2u(__floats2half2_rn(nvy.x, nvy.y)); \
            if (hq >= 0) sbw[w][hm][BUF][hwd] = h2u(__floats2half2_rn(nvh.x, nvh.y)); \
        }

    // prologue: stage row 0 into buf 0
    STAGE_LOAD(0);
    STAGE_WRITE(0);
    asm volatile("s_waitcnt lgkmcnt(0)" ::: "memory");

    __half2 ring[5][11];     // x, y, xx, yy, xy — static indices only
    float acc = 0.f;
    const float C1 = 1e-4f, C2 = 9e-4f;
    const __half2 hz = __float2half2_rn(0.f);

    #pragma unroll 1
    for (int jb = 0; jb < 44; jb += 11) {
        #pragma unroll
        for (int ph = 0; ph < 11; ++ph) {
            const int j = jb + ph;          // j % 11 == ph
            if (j < NI) {
                const int cur = j & 1, nxt = cur ^ 1;

                // issue next-row global loads early (hide HBM latency)
                if (j + 1 < NI) STAGE_LOAD(j + 1);

                // read 7-word windows (stride-1, conflict-free)
                unsigned Dx[7], Dy[7];
                #pragma unroll
                for (int k2 = 0; k2 < 7; ++k2) Dx[k2] = sbw[w][0][cur][lane + k2];
                #pragma unroll
                for (int k2 = 0; k2 < 7; ++k2) Dy[k2] = sbw[w][1][cur][lane + k2];

                // h-pass: 11 taps; even k -> funnel-shifted view, odd k -> direct
                __half2 hx = hz, hy = hz, hxx = hz, hyy = hz, hxy = hz;
                #pragma unroll
                for (int k = 0; k < 11; ++k) {
                    unsigned ux, uy;
                    if (k & 1) { ux = Dx[(k + 1) >> 1];            uy = Dy[(k + 1) >> 1]; }
                    else       { ux = fun16(Dx[(k >> 1) + 1], Dx[k >> 1]);
                                 uy = fun16(Dy[(k >> 1) + 1], Dy[k >> 1]); }
                    __half2 xk = u2h(ux), yk = u2h(uy);
                    __half2 wx = __hmul2(w2[k], xk);
                    __half2 wy = __hmul2(w2[k], yk);
                    hx  = __hadd2(hx, wx);
                    hy  = __hadd2(hy, wy);
                    hxx = __hfma2(wx, xk, hxx);
                    hyy = __hfma2(wy, yk, hyy);
                    hxy = __hfma2(wx, yk, hxy);
                }
                ring[0][ph] = hx;  ring[1][ph] = hy;
                ring[2][ph] = hxx; ring[3][ph] = hyy; ring[4][ph] = hxy;

                // v-pass from ring (valid once j >= 10)
                if (j >= 10) {
                    __half2 mu1 = hz, mu2 = hz, vxx = hz, vyy = hz, vxy = hz;
                    #pragma unroll
                    for (int k = 0; k < 11; ++k) {
                        const int s = (ph + 1 + k) % 11;
                        mu1 = __hfma2(w2[k], ring[0][s], mu1);
                        mu2 = __hfma2(w2[k], ring[1][s], mu2);
                        vxx = __hfma2(w2[k], ring[2][s], vxx);
                        vyy = __hfma2(w2[k], ring[3][s], vyy);
                        vxy = __hfma2(w2[k], ring[4][s], vxy);
                    }
                    float2 m1 = __half22float2(mu1);
                    float2 m2 = __half22float2(mu2);
                    float2 xx = __half22float2(vxx);
                    float2 yy = __half22float2(vyy);
                    float2 xy = __half22float2(vxy);
                    #pragma unroll
                    for (int h = 0; h < 2; ++h) {
                        float a1 = h ? m1.y : m1.x;
                        float a2 = h ? m2.y : m2.x;
                        float bx = h ? xx.y : xx.x;
                        float by = h ? yy.y : yy.x;
                        float bz = h ? xy.y : xy.x;
                        float m11 = a1 * a1, m22 = a2 * a2, m12 = a1 * a2;
                        float s1 = bx - m11, s2 = by - m22, s12 = bz - m12;
                        float num = (2.f * m12 + C1) * (2.f * s12 + C2);
                        float den = (m11 + m22 + C1) * (s1 + s2 + C2);
                        acc = fmaf(num, __builtin_amdgcn_rcpf(den), acc);
                    }
                }

                // write next row into the other buffer (wave-private, no barrier)
                if (j + 1 < NI) STAGE_WRITE(nxt);
                asm volatile("s_waitcnt lgkmcnt(0)" ::: "memory");
            }
        }
    }

    // wave reduction; each wave owns its strip's partial
    #pragma unroll
    for (int off = 32; off > 0; off >>= 1)
        acc += __shfl_down(acc, off, 64);
    if (lane == 0) partial[sid] = acc;
}

__global__ __launch_bounds__(256) void ssim_reduce_kernel(
    const float* __restrict__ partial, float* __restrict__ out)
{
    const int tid = threadIdx.x;
    double s = 0.0;
    for (int i = tid; i < NSTRIP; i += 256) s += (double)partial[i];
    __shared__ double sd[256];
    sd[tid] = s;
    __syncthreads();
    for (int off = 128; off > 0; off >>= 1) {
        if (tid < off) sd[tid] += sd[tid + off];
        __syncthreads();
    }
    if (tid == 0) out[0] = (float)(1.0 - sd[0] / NPIX);
}

extern "C" void kernel_launch(void* const* d_in, const int* in_sizes, int n_in,
                              void* d_out, int out_size, void* d_ws, size_t ws_size,
                              hipStream_t stream) {
    const float* X = (const float*)d_in[0];
    const float* Y = (const float*)d_in[1];
    float* partial = (float*)d_ws;   // NSTRIP floats = 12 KiB
    float* out = (float*)d_out;

    ssim_sweep_kernel<<<NBLK, 256, 0, stream>>>(X, Y, partial);
    ssim_reduce_kernel<<<1, 256, 0, stream>>>(partial, out);
}